// Round 5
// baseline (317.302 us; speedup 1.0000x reference)
//
#include <hip/hip_runtime.h>
#include <hip/hip_bf16.h>
#include <math.h>

// Problem constants
#define B  16384
#define K  1024
#define D  512
#define TAU_INV 10.0f
#define EPS 1e-12f

typedef unsigned short ushort_t;

// d_out layout (floats): [0, B*D) pt ; [B*D, B*D+K*D) p ; then sim_loss, div_loss
#define OUT_PT   0
#define OUT_P    (B*D)
#define OUT_SIM  (B*D + K*D)
#define OUT_DIV  (B*D + K*D + 1)

// ws layout (floats):
//  [0..16)        scalars: 2=diag sum
//  [1024,2048)    softmax per-block dot partials (1024)
//  [2048,2560)    colsum[512] (atomic-accumulated)
//  [32768, +B*K/2) simh f16 [B][1024]; after softmax same bytes hold Eh f16
//  then Ph  [1024][512] f16  (1 MB)  — gemm1 B operand
//  then PTh [512][1024] f16  (1 MB)  — gemm2 B operand (p transposed)
#define WS_DIAG  2
#define WS_RED   1024
#define WS_COL   2048
#define WS_SIM   32768
#define WS_PH    (WS_SIM + (B*K)/2)
#define WS_PTH   (WS_PH + (K*D)/2)

// Xh f16 [16384][512] (16 MB) lives in d_out's pt region, consumed by gemm1
// before gemm2 overwrites pt.

typedef _Float16 half8 __attribute__((ext_vector_type(8)));
typedef float f32x4 __attribute__((ext_vector_type(4)));

__device__ __forceinline__ float wave_reduce_sum(float v) {
    #pragma unroll
    for (int off = 32; off >= 1; off >>= 1) v += __shfl_down(v, off);
    return v;
}
__device__ __forceinline__ float wave_reduce_max(float v) {
    #pragma unroll
    for (int off = 32; off >= 1; off >>= 1) v = fmaxf(v, __shfl_down(v, off));
    return v;
}

__device__ __forceinline__ ushort_t f2h(float f) {
    _Float16 h = (_Float16)f;
    return __builtin_bit_cast(ushort_t, h);
}
__device__ __forceinline__ float h2f(ushort_t u) {
    return (float)__builtin_bit_cast(_Float16, u);
}

// Zero scalars + colsum
__global__ __launch_bounds__(256) void zero_ws(float* ws) {
    int t = threadIdx.x;
    if (t < 16) ws[t] = 0.0f;
    ws[WS_COL + t] = 0.0f;
    ws[WS_COL + 256 + t] = 0.0f;
}

// Normalize prototypes: one wave per row. Writes phat (fp32) to d_out.
__global__ __launch_bounds__(256) void norm_p_kernel(const float* __restrict__ proto,
                                                     float* __restrict__ out,
                                                     float* __restrict__ ws) {
    int wid = threadIdx.x >> 6, lane = threadIdx.x & 63;
    int row = blockIdx.x * 4 + wid;
    const float4* pr = (const float4*)(proto + (size_t)row * D);
    float4 a = pr[lane * 2], b = pr[lane * 2 + 1];
    float ss = a.x*a.x + a.y*a.y + a.z*a.z + a.w*a.w
             + b.x*b.x + b.y*b.y + b.z*b.z + b.w*b.w;
    ss = wave_reduce_sum(ss);
    ss = __shfl(ss, 0);
    float inv = 1.0f / fmaxf(sqrtf(ss), EPS);
    float4* po = (float4*)(out + OUT_P + (size_t)row * D);
    po[lane * 2]     = make_float4(a.x*inv, a.y*inv, a.z*inv, a.w*inv);
    po[lane * 2 + 1] = make_float4(b.x*inv, b.y*inv, b.z*inv, b.w*inv);
    __shared__ float red[4];
    if (lane == 0) red[wid] = ss * inv * inv;
    __syncthreads();
    if (threadIdx.x == 0)
        atomicAdd(ws + WS_DIAG, red[0] + red[1] + red[2] + red[3]);
}

// Ph [1024][512] f16
__global__ __launch_bounds__(256) void pcvt_kernel(const float* __restrict__ out,
                                                   ushort_t* __restrict__ Ph) {
    int k = blockIdx.x, tid = threadIdx.x;
    const float2* pr = (const float2*)(out + OUT_P + (size_t)k * D);
    float2 v = pr[tid];
    *(ushort2*)(Ph + (size_t)k * D + 2 * tid) = make_ushort2(f2h(v.x), f2h(v.y));
}

// PTh [512][1024] f16: transpose of phat
__global__ __launch_bounds__(256) void ptcvt_kernel(const float* __restrict__ out,
                                                    ushort_t* __restrict__ PT) {
    __shared__ float tile[64][65];
    int k0 = blockIdx.x * 64, d0 = blockIdx.y * 64;
    int tid = threadIdx.x;
    const float* phat = out + OUT_P;
    #pragma unroll
    for (int i = tid; i < 64 * 64; i += 256) {
        int kk = i >> 6, dd = i & 63;
        tile[dd][kk] = phat[(size_t)(k0 + kk) * D + d0 + dd];
    }
    __syncthreads();
    #pragma unroll
    for (int i = tid; i < 64 * 64; i += 256) {
        int dd = i >> 6, kk = i & 63;
        PT[(size_t)(d0 + dd) * K + k0 + kk] = f2h(tile[dd][kk]);
    }
}

// Column-sum partials: 32 blocks, coalesced, low-contention atomics.
__global__ __launch_bounds__(256) void col_partial(const float* __restrict__ out,
                                                   float* __restrict__ ws) {
    int d = threadIdx.x * 2;
    const float* p = out + OUT_P + (size_t)blockIdx.x * 32 * D;
    float sx = 0.0f, sy = 0.0f;
    #pragma unroll
    for (int kk = 0; kk < 32; ++kk) {
        float2 v = *(const float2*)(p + (size_t)kk * D + d);
        sx += v.x; sy += v.y;
    }
    atomicAdd(ws + WS_COL + d, sx);
    atomicAdd(ws + WS_COL + d + 1, sy);
}

// Fused x row-norm + f16 convert: Xh [16384][512] in out's pt region.
__global__ __launch_bounds__(256) void xcvt_kernel(const float* __restrict__ x,
                                                   ushort_t* __restrict__ Xh) {
    int wid = threadIdx.x >> 6, lane = threadIdx.x & 63;
    int row = blockIdx.x * 4 + wid;
    const float4* xr = (const float4*)(x + (size_t)row * D);
    float4 a = xr[lane * 2], b = xr[lane * 2 + 1];
    float ss = a.x*a.x + a.y*a.y + a.z*a.z + a.w*a.w
             + b.x*b.x + b.y*b.y + b.z*b.z + b.w*b.w;
    ss = wave_reduce_sum(ss);
    ss = __shfl(ss, 0);
    float inv = 1.0f / fmaxf(sqrtf(ss), EPS);
    ushort4 h0 = make_ushort4(f2h(a.x*inv), f2h(a.y*inv), f2h(a.z*inv), f2h(a.w*inv));
    ushort4 h1 = make_ushort4(f2h(b.x*inv), f2h(b.y*inv), f2h(b.z*inv), f2h(b.w*inv));
    ushort4* xo = (ushort4*)(Xh + (size_t)row * D);
    xo[lane * 2]     = h0;
    xo[lane * 2 + 1] = h1;
}

// Barrier-free direct-MFMA GEMM: C[m][n] = A·B^T, f16 inputs.
// Block = 4 waves; each wave owns a PRIVATE 32(m)x128(n) tile (2x8 MFMA tiles).
// A and B fragments load straight from global into VGPRs (no LDS, no
// __syncthreads): B operand is ~1-2 MB -> L1/L2-resident; A is streamed.
// Per kc: 2 A-frag + 8 B-frag 16B loads (quads form 64B/row segments),
// 16 MFMA. K-offsets are compile-time immediates under unroll.
// F16C: write C as f16 (for simh), else fp32.
template<int LDA, int LDB, int LDC, int KK, bool F16C>
__global__ __launch_bounds__(256, 2) void gemm_direct(const ushort_t* __restrict__ A,
                                                      const ushort_t* __restrict__ Bm,
                                                      void* __restrict__ Cv) {
    int tid = threadIdx.x;
    int wid = tid >> 6, lane = tid & 63;
    int quad = lane >> 4, l16 = lane & 15;
    int m0 = blockIdx.y * 128 + wid * 32;
    int n0 = blockIdx.x * 128;

    const ushort_t* Ap = A + (size_t)(m0 + l16) * LDA + quad * 8;
    const ushort_t* Bp = Bm + (size_t)(n0 + l16) * LDB + quad * 8;

    f32x4 acc[2][8] = {};

    #pragma unroll 8
    for (int kc = 0; kc < KK; kc += 32) {
        half8 af[2], bg[8];
        #pragma unroll
        for (int i = 0; i < 2; ++i)
            af[i] = *(const half8*)(Ap + kc + (size_t)(16 * i) * LDA);
        #pragma unroll
        for (int j = 0; j < 8; ++j)
            bg[j] = *(const half8*)(Bp + kc + (size_t)(16 * j) * LDB);
        #pragma unroll
        for (int i = 0; i < 2; ++i)
            #pragma unroll
            for (int j = 0; j < 8; ++j)
                acc[i][j] = __builtin_amdgcn_mfma_f32_16x16x32_f16(af[i], bg[j], acc[i][j], 0, 0, 0);
    }

    #pragma unroll
    for (int i = 0; i < 2; ++i) {
        #pragma unroll
        for (int j = 0; j < 8; ++j) {
            #pragma unroll
            for (int r = 0; r < 4; ++r) {
                int row = m0 + 16 * i + quad * 4 + r;
                int col = n0 + 16 * j + l16;
                if (F16C)
                    ((ushort_t*)Cv)[(size_t)row * LDC + col] = f2h(acc[i][j][r]);
                else
                    ((float*)Cv)[(size_t)row * LDC + col] = acc[i][j][r];
            }
        }
    }
}

// Row softmax with gumbel. One WAVE per row, 4 rows/wave. Reads simh f16,
// writes Eh f16 in-place. Per-block dot partial (no contended atomics).
__global__ __launch_bounds__(256) void softmax_rows(const float* __restrict__ u,
                                                    float* __restrict__ ws) {
    ushort_t* simh = (ushort_t*)(ws + WS_SIM);
    int tid = threadIdx.x;
    int wid = tid >> 6, lane = tid & 63;
    int gw = blockIdx.x * 4 + wid;        // 0..4095
    float dotacc = 0.0f;

    for (int r = 0; r < 4; ++r) {
        int row = gw + 4096 * r;
        ushort4* srow = (ushort4*)(simh + (size_t)row * K);
        const float4* urow = (const float4*)(u + (size_t)row * K);
        float4 s[4], z[4];
        #pragma unroll
        for (int j = 0; j < 4; ++j) {
            ushort4 sh = srow[lane + 64 * j];
            float4 uu = urow[lane + 64 * j];
            s[j] = make_float4(h2f(sh.x), h2f(sh.y), h2f(sh.z), h2f(sh.w));
            z[j].x = (s[j].x - logf(-logf(uu.x))) * TAU_INV;
            z[j].y = (s[j].y - logf(-logf(uu.y))) * TAU_INV;
            z[j].z = (s[j].z - logf(-logf(uu.z))) * TAU_INV;
            z[j].w = (s[j].w - logf(-logf(uu.w))) * TAU_INV;
        }
        float m = z[0].x;
        #pragma unroll
        for (int j = 0; j < 4; ++j)
            m = fmaxf(m, fmaxf(fmaxf(z[j].x, z[j].y), fmaxf(z[j].z, z[j].w)));
        m = wave_reduce_max(m);
        m = __shfl(m, 0);

        float4 e[4];
        float l = 0.0f;
        #pragma unroll
        for (int j = 0; j < 4; ++j) {
            e[j].x = expf(z[j].x - m);
            e[j].y = expf(z[j].y - m);
            e[j].z = expf(z[j].z - m);
            e[j].w = expf(z[j].w - m);
            l += e[j].x + e[j].y + e[j].z + e[j].w;
        }
        l = wave_reduce_sum(l);
        l = __shfl(l, 0);
        float inv = 1.0f / l;

        #pragma unroll
        for (int j = 0; j < 4; ++j) {
            float ex = e[j].x * inv, ey = e[j].y * inv,
                  ez = e[j].z * inv, ew = e[j].w * inv;
            srow[lane + 64 * j] = make_ushort4(f2h(ex), f2h(ey), f2h(ez), f2h(ew));
            dotacc += ex * s[j].x + ey * s[j].y + ez * s[j].z + ew * s[j].w;
        }
    }

    dotacc = wave_reduce_sum(dotacc);
    __shared__ float red[4];
    if (lane == 0) red[wid] = dotacc;
    __syncthreads();
    if (tid == 0) ws[WS_RED + blockIdx.x] = red[0] + red[1] + red[2] + red[3];
}

__global__ __launch_bounds__(256) void finalize_kernel(float* __restrict__ out,
                                                       const float* __restrict__ ws) {
    int tid = threadIdx.x, wid = tid >> 6, lane = tid & 63;
    float vdot = 0.0f;
    #pragma unroll
    for (int i = 0; i < 4; ++i) vdot += ws[WS_RED + tid + 256 * i];
    float c0 = ws[WS_COL + tid], c1 = ws[WS_COL + 256 + tid];
    float vssq = c0 * c0 + c1 * c1;
    vdot = wave_reduce_sum(vdot);
    vssq = wave_reduce_sum(vssq);
    __shared__ float rd[4], rs[4];
    if (lane == 0) { rd[wid] = vdot; rs[wid] = vssq; }
    __syncthreads();
    if (tid == 0) {
        float dot = rd[0] + rd[1] + rd[2] + rd[3];
        float ssq = rs[0] + rs[1] + rs[2] + rs[3];
        out[OUT_SIM] = 1.0f - dot * (1.0f / (float)B);
        out[OUT_DIV] = ssq - ws[WS_DIAG];
    }
}

extern "C" void kernel_launch(void* const* d_in, const int* in_sizes, int n_in,
                              void* d_out, int out_size, void* d_ws, size_t ws_size,
                              hipStream_t stream) {
    const float* input  = (const float*)d_in[0];
    const float* proto  = (const float*)d_in[1];
    const float* gumbel = (const float*)d_in[2];
    float* out = (float*)d_out;
    float* ws  = (float*)d_ws;

    ushort_t* Xh   = (ushort_t*)(out + OUT_PT);     // f16 x-hat in pt region
    ushort_t* Ph   = (ushort_t*)(ws + WS_PH);
    ushort_t* PTh  = (ushort_t*)(ws + WS_PTH);
    ushort_t* simh = (ushort_t*)(ws + WS_SIM);      // f16 sim, then Eh in-place

    zero_ws<<<1, 256, 0, stream>>>(ws);
    norm_p_kernel<<<K / 4, 256, 0, stream>>>(proto, out, ws);
    pcvt_kernel<<<K, 256, 0, stream>>>(out, Ph);
    {
        dim3 grid(K / 64, D / 64);
        ptcvt_kernel<<<grid, 256, 0, stream>>>(out, PTh);
    }
    col_partial<<<K / 32, 256, 0, stream>>>(out, ws);
    xcvt_kernel<<<B / 4, 256, 0, stream>>>(input, Xh);
    {
        // simh = Xh · Ph^T   (A: [B][512], B: [K][512], C: [B][K] f16)
        dim3 grid(K / 128, B / 128);
        gemm_direct<512, 512, K, 512, true><<<grid, 256, 0, stream>>>(Xh, Ph, simh);
    }
    softmax_rows<<<1024, 256, 0, stream>>>(gumbel, ws);
    {
        // pt = Eh · PTh^T   (A: [B][1024] f16, B: [512][1024], C: [B][512] fp32)
        dim3 grid(D / 128, B / 128);
        gemm_direct<1024, 1024, D, 1024, false><<<grid, 256, 0, stream>>>(simh, PTh, out + OUT_PT);
    }
    finalize_kernel<<<1, 256, 0, stream>>>(out, ws);
}

// Round 6
// 217.672 us; speedup vs baseline: 1.4577x; 1.4577x over previous
//
#include <hip/hip_runtime.h>
#include <math.h>

// Problem constants
#define B  16384
#define K  1024
#define D  512
#define TAU_INV 10.0f
#define EPS 1e-12f

typedef unsigned short ushort_t;

// d_out layout (floats): [0, B*D) pt ; [B*D, B*D+K*D) p ; then sim_loss, div_loss
#define OUT_PT   0
#define OUT_P    (B*D)
#define OUT_SIM  (B*D + K*D)
#define OUT_DIV  (B*D + K*D + 1)

// ws layout (floats):
//  [1024,2048)      softmax per-block dot partials (1024)
//  [32768, +B*K/2)  simh f16 [B][1024]; after softmax same bytes hold Eh f16
//  then Ph   [1024][512] f16 (1 MB)
//  then PTh  [512][1024] f16 (1 MB)
//  then DIAGP[256], COLP[256][512]  (norm_p per-block partials, no atomics)
#define WS_RED   1024
#define WS_SIM   32768
#define WS_PH    (WS_SIM + (B*K)/2)
#define WS_PTH   (WS_PH + (K*D)/2)
#define WS_DIAGP (WS_PTH + (K*D)/2)
#define WS_COLP  (WS_DIAGP + 256)

// Xh f16 [16384][512] (16 MB) lives in d_out's pt region, consumed by gemm1
// before gemm2 overwrites pt.

typedef _Float16 half8 __attribute__((ext_vector_type(8)));
typedef float f32x4 __attribute__((ext_vector_type(4)));

__device__ __forceinline__ float wave_reduce_sum(float v) {
    #pragma unroll
    for (int off = 32; off >= 1; off >>= 1) v += __shfl_down(v, off);
    return v;
}
__device__ __forceinline__ float wave_reduce_max(float v) {
    #pragma unroll
    for (int off = 32; off >= 1; off >>= 1) v = fmaxf(v, __shfl_down(v, off));
    return v;
}

__device__ __forceinline__ ushort_t f2h(float f) {
    _Float16 h = (_Float16)f;
    return __builtin_bit_cast(ushort_t, h);
}
__device__ __forceinline__ float h2f(ushort_t u) {
    return (float)__builtin_bit_cast(_Float16, u);
}

__device__ __forceinline__ void async16(const void* g, void* l) {
    __builtin_amdgcn_global_load_lds(
        (const __attribute__((address_space(1))) unsigned int*)g,
        (__attribute__((address_space(3))) unsigned int*)l, 16, 0, 0);
}

// Normalize prototypes (one wave per row, 4 rows/block). Fused outputs:
//  - phat fp32 -> d_out (output 1)
//  - Ph f16 [1024][512]
//  - per-block colsum partial [512] -> ws[WS_COLP + blk*512]
//  - per-block diag partial -> ws[WS_DIAGP + blk]
// No atomics anywhere.
__global__ __launch_bounds__(256) void norm_p_kernel(const float* __restrict__ proto,
                                                     float* __restrict__ out,
                                                     float* __restrict__ ws,
                                                     ushort_t* __restrict__ Ph) {
    __shared__ float cs[4][512];
    __shared__ float red[4];
    int tid = threadIdx.x, wid = tid >> 6, lane = tid & 63;
    int row = blockIdx.x * 4 + wid;
    const float4* pr = (const float4*)(proto + (size_t)row * D);
    float4 a = pr[lane * 2], b = pr[lane * 2 + 1];
    float ss = a.x*a.x + a.y*a.y + a.z*a.z + a.w*a.w
             + b.x*b.x + b.y*b.y + b.z*b.z + b.w*b.w;
    ss = wave_reduce_sum(ss);
    ss = __shfl(ss, 0);
    float inv = 1.0f / fmaxf(sqrtf(ss), EPS);
    float4 na = make_float4(a.x*inv, a.y*inv, a.z*inv, a.w*inv);
    float4 nb = make_float4(b.x*inv, b.y*inv, b.z*inv, b.w*inv);
    float4* po = (float4*)(out + OUT_P + (size_t)row * D);
    po[lane * 2]     = na;
    po[lane * 2 + 1] = nb;
    ushort4* ph = (ushort4*)(Ph + (size_t)row * D);
    ph[lane * 2]     = make_ushort4(f2h(na.x), f2h(na.y), f2h(na.z), f2h(na.w));
    ph[lane * 2 + 1] = make_ushort4(f2h(nb.x), f2h(nb.y), f2h(nb.z), f2h(nb.w));
    *(float4*)(&cs[wid][lane * 8])     = na;
    *(float4*)(&cs[wid][lane * 8 + 4]) = nb;
    if (lane == 0) red[wid] = ss * inv * inv;
    __syncthreads();
    float c0 = cs[0][tid] + cs[1][tid] + cs[2][tid] + cs[3][tid];
    float c1 = cs[0][tid + 256] + cs[1][tid + 256] + cs[2][tid + 256] + cs[3][tid + 256];
    ws[WS_COLP + (size_t)blockIdx.x * 512 + tid]       = c0;
    ws[WS_COLP + (size_t)blockIdx.x * 512 + tid + 256] = c1;
    if (tid == 0) ws[WS_DIAGP + blockIdx.x] = red[0] + red[1] + red[2] + red[3];
}

// PTh [512][1024] f16: transpose of phat
__global__ __launch_bounds__(256) void ptcvt_kernel(const float* __restrict__ out,
                                                    ushort_t* __restrict__ PT) {
    __shared__ float tile[64][65];
    int k0 = blockIdx.x * 64, d0 = blockIdx.y * 64;
    int tid = threadIdx.x;
    const float* phat = out + OUT_P;
    #pragma unroll
    for (int i = tid; i < 64 * 64; i += 256) {
        int kk = i >> 6, dd = i & 63;
        tile[dd][kk] = phat[(size_t)(k0 + kk) * D + d0 + dd];
    }
    __syncthreads();
    #pragma unroll
    for (int i = tid; i < 64 * 64; i += 256) {
        int dd = i >> 6, kk = i & 63;
        PT[(size_t)(d0 + dd) * K + k0 + kk] = f2h(tile[dd][kk]);
    }
}

// Fused x row-norm + f16 convert: Xh [16384][512] in out's pt region.
__global__ __launch_bounds__(256) void xcvt_kernel(const float* __restrict__ x,
                                                   ushort_t* __restrict__ Xh) {
    int wid = threadIdx.x >> 6, lane = threadIdx.x & 63;
    int row = blockIdx.x * 4 + wid;
    const float4* xr = (const float4*)(x + (size_t)row * D);
    float4 a = xr[lane * 2], b = xr[lane * 2 + 1];
    float ss = a.x*a.x + a.y*a.y + a.z*a.z + a.w*a.w
             + b.x*b.x + b.y*b.y + b.z*b.z + b.w*b.w;
    ss = wave_reduce_sum(ss);
    ss = __shfl(ss, 0);
    float inv = 1.0f / fmaxf(sqrtf(ss), EPS);
    ushort4 h0 = make_ushort4(f2h(a.x*inv), f2h(a.y*inv), f2h(a.z*inv), f2h(a.w*inv));
    ushort4 h1 = make_ushort4(f2h(b.x*inv), f2h(b.y*inv), f2h(b.z*inv), f2h(b.w*inv));
    ushort4* xo = (ushort4*)(Xh + (size_t)row * D);
    xo[lane * 2]     = h0;
    xo[lane * 2 + 1] = h1;
}

// f16 bt-GEMM, BK=64 via TWO independent 32-k panels (m97 recipe per panel):
// 128x128 block tile, 4 waves (2x2), 4x4 16x16x32-f16 MFMA tiles per wave per
// panel -> 32 MFMA per barrier pair. global_load_lds width-16 staging.
// F16C: write C as f16 (for simh), else fp32.
template<int LDA, int LDB, int LDC, int KK, bool F16C>
__global__ __launch_bounds__(256) void gemm_bt2(const ushort_t* __restrict__ A,
                                                const ushort_t* __restrict__ Bm,
                                                void* __restrict__ Cv) {
    __shared__ __align__(16) ushort_t As[2 * 128 * 32];
    __shared__ __align__(16) ushort_t Bs[2 * 128 * 32];
    int tid = threadIdx.x;
    int wid = tid >> 6, lane = tid & 63;
    int quad = lane >> 4, l16 = lane & 15;
    int wm = (wid & 1) * 64, wn = (wid >> 1) * 64;
    int bn0 = blockIdx.x * 128, bm0 = blockIdx.y * 128;
    int ldrow = lane >> 2;           // 0..15
    int lcol  = (lane & 3) * 8;      // halves within a 32-half panel row

    f32x4 acc[4][4] = {};

    // wave-uniform LDS staging bases: panel p, row-group q
    ushort_t* AsD[2][2] = {
        { As + (wid * 16) * 32,        As + (64 + wid * 16) * 32 },
        { As + 4096 + (wid * 16) * 32, As + 4096 + (64 + wid * 16) * 32 } };
    ushort_t* BsD[2][2] = {
        { Bs + (wid * 16) * 32,        Bs + (64 + wid * 16) * 32 },
        { Bs + 4096 + (wid * 16) * 32, Bs + 4096 + (64 + wid * 16) * 32 } };

    const ushort_t* Ab = A + (size_t)(bm0 + wid * 16 + ldrow) * LDA + lcol;
    const ushort_t* Bb = Bm + (size_t)(bn0 + wid * 16 + ldrow) * LDB + lcol;

    for (int kc = 0; kc < KK; kc += 64) {
        async16(Ab + kc,                       AsD[0][0]);
        async16(Ab + kc + (size_t)64 * LDA,    AsD[0][1]);
        async16(Ab + kc + 32,                  AsD[1][0]);
        async16(Ab + kc + 32 + (size_t)64*LDA, AsD[1][1]);
        async16(Bb + kc,                       BsD[0][0]);
        async16(Bb + kc + (size_t)64 * LDB,    BsD[0][1]);
        async16(Bb + kc + 32,                  BsD[1][0]);
        async16(Bb + kc + 32 + (size_t)64*LDB, BsD[1][1]);
        __syncthreads();
        #pragma unroll
        for (int p = 0; p < 2; ++p) {
            half8 af[4], bg[4];
            #pragma unroll
            for (int i = 0; i < 4; ++i)
                af[i] = *(const half8*)(As + p * 4096 + (wm + 16 * i + l16) * 32 + quad * 8);
            #pragma unroll
            for (int j = 0; j < 4; ++j)
                bg[j] = *(const half8*)(Bs + p * 4096 + (wn + 16 * j + l16) * 32 + quad * 8);
            #pragma unroll
            for (int i = 0; i < 4; ++i)
                #pragma unroll
                for (int j = 0; j < 4; ++j)
                    acc[i][j] = __builtin_amdgcn_mfma_f32_16x16x32_f16(af[i], bg[j], acc[i][j], 0, 0, 0);
        }
        __syncthreads();
    }
    #pragma unroll
    for (int i = 0; i < 4; ++i) {
        #pragma unroll
        for (int j = 0; j < 4; ++j) {
            #pragma unroll
            for (int r = 0; r < 4; ++r) {
                int row = bm0 + wm + 16 * i + quad * 4 + r;
                int col = bn0 + wn + 16 * j + l16;
                if (F16C)
                    ((ushort_t*)Cv)[(size_t)row * LDC + col] = f2h(acc[i][j][r]);
                else
                    ((float*)Cv)[(size_t)row * LDC + col] = acc[i][j][r];
            }
        }
    }
}

// Row softmax with gumbel. One WAVE per row, 4 rows/wave. Reads simh f16,
// writes Eh f16 in-place. Per-block dot partial (no contended atomics).
__global__ __launch_bounds__(256) void softmax_rows(const float* __restrict__ u,
                                                    float* __restrict__ ws) {
    ushort_t* simh = (ushort_t*)(ws + WS_SIM);
    int tid = threadIdx.x;
    int wid = tid >> 6, lane = tid & 63;
    int gw = blockIdx.x * 4 + wid;        // 0..4095
    float dotacc = 0.0f;

    for (int r = 0; r < 4; ++r) {
        int row = gw + 4096 * r;
        ushort4* srow = (ushort4*)(simh + (size_t)row * K);
        const float4* urow = (const float4*)(u + (size_t)row * K);
        float4 s[4], z[4];
        #pragma unroll
        for (int j = 0; j < 4; ++j) {
            ushort4 sh = srow[lane + 64 * j];
            float4 uu = urow[lane + 64 * j];
            s[j] = make_float4(h2f(sh.x), h2f(sh.y), h2f(sh.z), h2f(sh.w));
            z[j].x = (s[j].x - logf(-logf(uu.x))) * TAU_INV;
            z[j].y = (s[j].y - logf(-logf(uu.y))) * TAU_INV;
            z[j].z = (s[j].z - logf(-logf(uu.z))) * TAU_INV;
            z[j].w = (s[j].w - logf(-logf(uu.w))) * TAU_INV;
        }
        float m = z[0].x;
        #pragma unroll
        for (int j = 0; j < 4; ++j)
            m = fmaxf(m, fmaxf(fmaxf(z[j].x, z[j].y), fmaxf(z[j].z, z[j].w)));
        m = wave_reduce_max(m);
        m = __shfl(m, 0);

        float4 e[4];
        float l = 0.0f;
        #pragma unroll
        for (int j = 0; j < 4; ++j) {
            e[j].x = expf(z[j].x - m);
            e[j].y = expf(z[j].y - m);
            e[j].z = expf(z[j].z - m);
            e[j].w = expf(z[j].w - m);
            l += e[j].x + e[j].y + e[j].z + e[j].w;
        }
        l = wave_reduce_sum(l);
        l = __shfl(l, 0);
        float inv = 1.0f / l;

        #pragma unroll
        for (int j = 0; j < 4; ++j) {
            float ex = e[j].x * inv, ey = e[j].y * inv,
                  ez = e[j].z * inv, ew = e[j].w * inv;
            srow[lane + 64 * j] = make_ushort4(f2h(ex), f2h(ey), f2h(ez), f2h(ew));
            dotacc += ex * s[j].x + ey * s[j].y + ez * s[j].z + ew * s[j].w;
        }
    }

    dotacc = wave_reduce_sum(dotacc);
    __shared__ float red[4];
    if (lane == 0) red[wid] = dotacc;
    __syncthreads();
    if (tid == 0) ws[WS_RED + blockIdx.x] = red[0] + red[1] + red[2] + red[3];
}

// Final reduction: softmax dot partials (1024), diag partials (256),
// colsum partials (256 x 512 -> ||colsum||^2).
__global__ __launch_bounds__(256) void finalize_kernel(float* __restrict__ out,
                                                       const float* __restrict__ ws) {
    int tid = threadIdx.x, wid = tid >> 6, lane = tid & 63;
    float vdot = 0.0f;
    #pragma unroll
    for (int i = 0; i < 4; ++i) vdot += ws[WS_RED + tid + 256 * i];
    float diag = ws[WS_DIAGP + tid];
    float c0 = 0.0f, c1 = 0.0f;
    for (int b2 = 0; b2 < 256; ++b2) {
        c0 += ws[WS_COLP + (size_t)b2 * 512 + tid];
        c1 += ws[WS_COLP + (size_t)b2 * 512 + tid + 256];
    }
    float vssq = c0 * c0 + c1 * c1;
    vdot = wave_reduce_sum(vdot);
    vssq = wave_reduce_sum(vssq);
    diag = wave_reduce_sum(diag);
    __shared__ float rd[4], rs[4], rg[4];
    if (lane == 0) { rd[wid] = vdot; rs[wid] = vssq; rg[wid] = diag; }
    __syncthreads();
    if (tid == 0) {
        float dot = rd[0] + rd[1] + rd[2] + rd[3];
        float ssq = rs[0] + rs[1] + rs[2] + rs[3];
        float dg  = rg[0] + rg[1] + rg[2] + rg[3];
        out[OUT_SIM] = 1.0f - dot * (1.0f / (float)B);
        out[OUT_DIV] = ssq - dg;
    }
}

extern "C" void kernel_launch(void* const* d_in, const int* in_sizes, int n_in,
                              void* d_out, int out_size, void* d_ws, size_t ws_size,
                              hipStream_t stream) {
    const float* input  = (const float*)d_in[0];
    const float* proto  = (const float*)d_in[1];
    const float* gumbel = (const float*)d_in[2];
    float* out = (float*)d_out;
    float* ws  = (float*)d_ws;

    ushort_t* Xh   = (ushort_t*)(out + OUT_PT);     // f16 x-hat in pt region
    ushort_t* Ph   = (ushort_t*)(ws + WS_PH);
    ushort_t* PTh  = (ushort_t*)(ws + WS_PTH);
    ushort_t* simh = (ushort_t*)(ws + WS_SIM);      // f16 sim, then Eh in-place

    norm_p_kernel<<<K / 4, 256, 0, stream>>>(proto, out, ws, Ph);
    {
        dim3 grid(K / 64, D / 64);
        ptcvt_kernel<<<grid, 256, 0, stream>>>(out, PTh);
    }
    xcvt_kernel<<<B / 4, 256, 0, stream>>>(input, Xh);
    {
        // simh = Xh · Ph^T   (A: [B][512], B: [K][512], C: [B][K] f16)
        dim3 grid(K / 128, B / 128);
        gemm_bt2<512, 512, K, 512, true><<<grid, 256, 0, stream>>>(Xh, Ph, simh);
    }
    softmax_rows<<<1024, 256, 0, stream>>>(gumbel, ws);
    {
        // pt = Eh · PTh^T   (A: [B][1024] f16, B: [512][1024], C: [B][512] fp32)
        dim3 grid(D / 128, B / 128);
        gemm_bt2<1024, 1024, D, 1024, false><<<grid, 256, 0, stream>>>(simh, PTh, out + OUT_PT);
    }
    finalize_kernel<<<1, 256, 0, stream>>>(out, ws);
}